// Round 1
// baseline (306.463 us; speedup 1.0000x reference)
//
#include <hip/hip_runtime.h>
#include <hip/hip_bf16.h>

#define BATCH 256
#define NPTS  4096
#define TLEN  30
#define KSEL  6

// One block per sample. 256 threads.
// Exact reproduction of the reference scan semantics:
//   - process candidates in descending score order, stable tie-break = lower index
//   - accept if d2 >= 4.0 to all previously accepted, stop accepting at K
//   - unfilled slots: sel_idx = 0 (sorted pos 0 == global argmax), sel_pts = 0
__global__ __launch_bounds__(256)
void nms_kernel(const float* __restrict__ coord,  // [B,1,N,2]
                const float* __restrict__ cls,    // [B,1,N]
                const float* __restrict__ traj,   // [B,1,N,T,2]
                const float* __restrict__ cent,   // [B,1,N]
                float* __restrict__ out)          // [B*K*T*2 | B*K | B*K*2]
{
    const int b   = blockIdx.x;
    const int tid = threadIdx.x;

    __shared__ float s_scores[NPTS];          // 16 KiB
    __shared__ float w_v[4];
    __shared__ int   w_i[4];
    __shared__ float s_selx[KSEL], s_sely[KSEL], s_selscore[KSEL];
    __shared__ int   s_selidx[KSEL];
    __shared__ int   s_count, s_done, s_firstidx;
    __shared__ float s_firstscore;

    const float* cls_b   = cls   + (size_t)b * NPTS;
    const float* cent_b  = cent  + (size_t)b * NPTS;
    const float* coord_b = coord + (size_t)b * NPTS * 2;

    for (int i = tid; i < NPTS; i += 256)
        s_scores[i] = cls_b[i] * cent_b[i];

    if (tid == 0) { s_count = 0; s_done = 0; s_firstidx = 0; s_firstscore = 0.0f; }
    __syncthreads();

    for (int iter = 0; iter < NPTS; ++iter) {
        // ---- block argmax with stable tie-break (smaller index wins ties) ----
        float bv = -2.0f;
        int   bi = NPTS;
        for (int i = tid; i < NPTS; i += 256) {
            float v = s_scores[i];
            if (v > bv || (v == bv && i < bi)) { bv = v; bi = i; }
        }
        for (int off = 32; off > 0; off >>= 1) {
            float ov = __shfl_down(bv, off, 64);
            int   oi = __shfl_down(bi, off, 64);
            if (ov > bv || (ov == bv && oi < bi)) { bv = ov; bi = oi; }
        }
        const int wave = tid >> 6, lane = tid & 63;
        if (lane == 0) { w_v[wave] = bv; w_i[wave] = bi; }
        __syncthreads();                              // (A)

        if (tid == 0) {
            bv = w_v[0]; bi = w_i[0];
            #pragma unroll
            for (int w = 1; w < 4; ++w) {
                if (w_v[w] > bv || (w_v[w] == bv && w_i[w] < bi)) { bv = w_v[w]; bi = w_i[w]; }
            }
            if (bv < 0.0f) {
                s_done = 1;                           // all candidates consumed
            } else {
                s_scores[bi] = -1.0f;                 // mark processed
                if (iter == 0) { s_firstidx = bi; s_firstscore = bv; }
                const float px = coord_b[2 * bi];
                const float py = coord_b[2 * bi + 1];
                bool conflict = false;
                const int cnt = s_count;
                for (int k = 0; k < cnt; ++k) {
                    const float dx = s_selx[k] - px;
                    const float dy = s_sely[k] - py;
                    if (dx * dx + dy * dy < 4.0f) conflict = true;
                }
                if (!conflict) {
                    s_selx[cnt] = px; s_sely[cnt] = py;
                    s_selscore[cnt] = bv; s_selidx[cnt] = bi;
                    s_count = cnt + 1;
                    if (cnt + 1 == KSEL) s_done = 1;
                }
            }
        }
        __syncthreads();                              // (B)
        if (s_done) break;
    }

    // ---- write outputs ----
    const int   cnt    = s_count;
    const int   fidx   = s_firstidx;
    const float fscore = s_firstscore;

    // pred_trajs: out[0 .. B*K*T*2)
    const float* traj_b   = traj + (size_t)b * NPTS * TLEN * 2;
    float*       out_traj = out  + (size_t)b * KSEL * TLEN * 2;
    for (int e = tid; e < KSEL * TLEN * 2; e += 256) {
        const int k = e / (TLEN * 2);
        const int j = e - k * (TLEN * 2);
        const int idx = (k < cnt) ? s_selidx[k] : fidx;
        out_traj[e] = traj_b[(size_t)idx * (TLEN * 2) + j];
    }

    // probs: out[B*K*T*2 .. +B*K)
    float* out_probs = out + (size_t)BATCH * KSEL * TLEN * 2;
    if (tid < KSEL)
        out_probs[b * KSEL + tid] = (tid < cnt) ? s_selscore[tid] : fscore;

    // goals: out[B*K*T*2 + B*K .. +B*K*2)  — zeros for unfilled slots
    float* out_goals = out + (size_t)BATCH * KSEL * TLEN * 2 + (size_t)BATCH * KSEL;
    if (tid >= 64 && tid < 64 + KSEL * 2) {
        const int e = tid - 64;
        const int k = e >> 1, d = e & 1;
        const float v = (k < cnt) ? (d ? s_sely[k] : s_selx[k]) : 0.0f;
        out_goals[(b * KSEL + k) * 2 + d] = v;
    }
}

extern "C" void kernel_launch(void* const* d_in, const int* in_sizes, int n_in,
                              void* d_out, int out_size, void* d_ws, size_t ws_size,
                              hipStream_t stream) {
    const float* coord = (const float*)d_in[0];  // [B,1,N,2]
    const float* cls   = (const float*)d_in[1];  // [B,1,N]
    const float* traj  = (const float*)d_in[2];  // [B,1,N,T,2]
    const float* cent  = (const float*)d_in[3];  // [B,1,N]
    float* out = (float*)d_out;

    nms_kernel<<<BATCH, 256, 0, stream>>>(coord, cls, traj, cent, out);
}

// Round 2
// 302.349 us; speedup vs baseline: 1.0136x; 1.0136x over previous
//
#include <hip/hip_runtime.h>
#include <hip/hip_bf16.h>

#define BATCH 256
#define NPTS  4096
#define TLEN  30
#define KSEL  6
#define THREADS 1024
#define NWAVES (THREADS / 64)

// One block per sample, 1024 threads (16 waves/CU) for latency hiding.
// Exact reproduction of the reference scan semantics:
//   - process candidates in descending score order, stable tie-break = lower index
//     (jnp.argsort is stable, so equal scores keep ascending-index order)
//   - accept if d2 >= 4.0 to all previously accepted, stop at K=6
//   - unfilled slots: sel_idx = 0 -> sorted pos 0 == global argmax; goals = 0
__global__ __launch_bounds__(THREADS)
void nms_kernel(const float* __restrict__ coord,  // [B,1,N,2]
                const float* __restrict__ cls,    // [B,1,N]
                const float* __restrict__ traj,   // [B,1,N,T,2]
                const float* __restrict__ cent,   // [B,1,N]
                float* __restrict__ out)          // [B*K*T*2 | B*K | B*K*2]
{
    const int b   = blockIdx.x;
    const int tid = threadIdx.x;

    __shared__ float s_scores[NPTS];          // 16 KiB
    __shared__ float w_v[NWAVES];
    __shared__ int   w_i[NWAVES];
    __shared__ float s_selx[KSEL], s_sely[KSEL], s_selscore[KSEL];
    __shared__ int   s_selidx[KSEL];
    __shared__ int   s_count, s_done, s_firstidx;
    __shared__ float s_firstscore;

    const float* cls_b   = cls   + (size_t)b * NPTS;
    const float* cent_b  = cent  + (size_t)b * NPTS;
    const float* coord_b = coord + (size_t)b * NPTS * 2;

    // ---- fused score compute (float4: exactly 1 round for 1024 threads) ----
    const float4 c4 = reinterpret_cast<const float4*>(cls_b)[tid];
    const float4 e4 = reinterpret_cast<const float4*>(cent_b)[tid];
    float p[4] = { c4.x * e4.x, c4.y * e4.y, c4.z * e4.z, c4.w * e4.w };
    reinterpret_cast<float4*>(s_scores)[tid] = make_float4(p[0], p[1], p[2], p[3]);

    if (tid == 0) { s_count = 0; s_done = 0; s_firstidx = 0; s_firstscore = 0.0f; }

    const int wave = tid >> 6, lane = tid & 63;

    for (int iter = 0; iter < NPTS; ++iter) {
        // ---- per-thread max over its 4 contiguous elements ----
        float bv;
        int   bi;
        if (iter == 0) {
            // straight from registers; ascending index + strict > keeps
            // the stable (lowest-index-wins) tie-break
            bv = p[0]; bi = tid * 4;
            #pragma unroll
            for (int j = 1; j < 4; ++j)
                if (p[j] > bv) { bv = p[j]; bi = tid * 4 + j; }
        } else {
            const float4 s4 = reinterpret_cast<const float4*>(s_scores)[tid];
            const float q[4] = { s4.x, s4.y, s4.z, s4.w };
            bv = q[0]; bi = tid * 4;
            #pragma unroll
            for (int j = 1; j < 4; ++j)
                if (q[j] > bv) { bv = q[j]; bi = tid * 4 + j; }
        }
        // ---- wave reduce (64 lanes) with stable tie-break ----
        #pragma unroll
        for (int off = 32; off > 0; off >>= 1) {
            const float ov = __shfl_down(bv, off, 64);
            const int   oi = __shfl_down(bi, off, 64);
            if (ov > bv || (ov == bv && oi < bi)) { bv = ov; bi = oi; }
        }
        if (lane == 0) { w_v[wave] = bv; w_i[wave] = bi; }
        __syncthreads();                              // (A)

        if (tid == 0) {
            bv = w_v[0]; bi = w_i[0];
            #pragma unroll
            for (int w = 1; w < NWAVES; ++w)
                if (w_v[w] > bv || (w_v[w] == bv && w_i[w] < bi)) { bv = w_v[w]; bi = w_i[w]; }
            if (bv < 0.0f) {
                s_done = 1;                           // all candidates consumed
            } else {
                s_scores[bi] = -1.0f;                 // mark processed
                if (iter == 0) { s_firstidx = bi; s_firstscore = bv; }
                const float px = coord_b[2 * bi];
                const float py = coord_b[2 * bi + 1];
                bool conflict = false;
                const int cnt = s_count;
                for (int k = 0; k < cnt; ++k) {
                    const float dx = s_selx[k] - px;
                    const float dy = s_sely[k] - py;
                    if (dx * dx + dy * dy < 4.0f) conflict = true;
                }
                if (!conflict) {
                    s_selx[cnt] = px; s_sely[cnt] = py;
                    s_selscore[cnt] = bv; s_selidx[cnt] = bi;
                    s_count = cnt + 1;
                    if (cnt + 1 == KSEL) s_done = 1;
                }
            }
        }
        __syncthreads();                              // (B)
        if (s_done) break;
    }

    // ---- write outputs ----
    const int   cnt    = s_count;
    const int   fidx   = s_firstidx;
    const float fscore = s_firstscore;

    // pred_trajs: out[0 .. B*K*T*2)   — 6 rows x 240 B, all 16B-aligned
    const float4* traj_b4   = reinterpret_cast<const float4*>(traj + (size_t)b * NPTS * TLEN * 2);
    float4*       out_traj4 = reinterpret_cast<float4*>(out + (size_t)b * KSEL * TLEN * 2);
    if (tid < KSEL * 15) {                            // 90 float4s = 6*30*2 floats
        const int k = tid / 15;
        const int j = tid - k * 15;
        const int idx = (k < cnt) ? s_selidx[k] : fidx;
        out_traj4[tid] = traj_b4[(size_t)idx * 15 + j];
    }

    // probs: out[B*K*T*2 .. +B*K)
    float* out_probs = out + (size_t)BATCH * KSEL * TLEN * 2;
    if (tid >= 128 && tid < 128 + KSEL) {
        const int k = tid - 128;
        out_probs[b * KSEL + k] = (k < cnt) ? s_selscore[k] : fscore;
    }

    // goals: out[B*K*T*2 + B*K .. +B*K*2)  — zeros for unfilled slots
    float* out_goals = out + (size_t)BATCH * KSEL * TLEN * 2 + (size_t)BATCH * KSEL;
    if (tid >= 192 && tid < 192 + KSEL * 2) {
        const int e = tid - 192;
        const int k = e >> 1, d = e & 1;
        const float v = (k < cnt) ? (d ? s_sely[k] : s_selx[k]) : 0.0f;
        out_goals[(b * KSEL + k) * 2 + d] = v;
    }
}

extern "C" void kernel_launch(void* const* d_in, const int* in_sizes, int n_in,
                              void* d_out, int out_size, void* d_ws, size_t ws_size,
                              hipStream_t stream) {
    const float* coord = (const float*)d_in[0];  // [B,1,N,2]
    const float* cls   = (const float*)d_in[1];  // [B,1,N]
    const float* traj  = (const float*)d_in[2];  // [B,1,N,T,2]
    const float* cent  = (const float*)d_in[3];  // [B,1,N]
    float* out = (float*)d_out;

    nms_kernel<<<BATCH, THREADS, 0, stream>>>(coord, cls, traj, cent, out);
}